// Round 4
// baseline (620.617 us; speedup 1.0000x reference)
//
#include <hip/hip_runtime.h>
#include <hip/hip_bf16.h>
#include <stdint.h>

typedef __attribute__((ext_vector_type(4))) float f32x4;
typedef __attribute__((ext_vector_type(4))) int   i32x4;
typedef __attribute__((ext_vector_type(8))) short s16x8;
typedef __attribute__((ext_vector_type(2))) unsigned int u32x2;

#define MFMA16x16x32 __builtin_amdgcn_mfma_f32_16x16x32_bf16

constexpr int NB = 64, NH = 16, SEQ = 256, DH = 128;
constexpr int KC = 32;               // k-chunk staged per iteration
constexpr float NEG_INF_F = -1.0e9f;

union Frag8 { uint32_t u[4]; s16x8 v; };

__device__ __forceinline__ uint32_t bf16_rne(float f) {
  uint32_t u = __builtin_bit_cast(uint32_t, f);
  return (u + 0x7fffu + ((u >> 16) & 1u)) >> 16;
}
__device__ __forceinline__ void cvt_hilo(float f, uint32_t& h, uint32_t& l) {
  h = bf16_rne(f);
  float hf = __builtin_bit_cast(float, h << 16);
  l = bf16_rne(f - hf);
}

// Fused attention: S^T = K·Q^T (swapped so P is lane-local), online softmax,
// O^T = V^T·P^T. All matmuls bf16x3 (hi*hi + hi*lo + lo*hi) == fp32-faithful.
__global__ __launch_bounds__(256, 3) void attn_fused(
    const float* __restrict__ Q, const float* __restrict__ K,
    const float* __restrict__ V, const float* __restrict__ Bias,
    const int* __restrict__ Mask, float* __restrict__ Out) {

  // K: row-major [KC][DH] bf16, 16B-chunk XOR swizzle (chunk ^= row&7)
  // V: interleaved [k/4][d ^ ((ksub&3)<<2)][k%4] bf16 so PV A-frags are 2x b64
  __shared__ short sKhi[KC * DH];
  __shared__ short sKlo[KC * DH];
  __shared__ short sVhi[KC * DH];
  __shared__ short sVlo[KC * DH];

  const int tid  = threadIdx.x;
  const int lane = tid & 63;
  const int w    = tid >> 6;       // wave 0..3
  const int col  = lane & 15;      // q (and d for PV A-frag rows)
  const int g    = lane >> 4;      // lane group 0..3

  const int wgid = blockIdx.x;
  const int bh   = wgid >> 2;      // (b*16 + h)
  const int qt   = wgid & 3;       // q-tile of 64 rows
  const int b    = bh >> 4;

  const int qglob = qt * 64 + w * 16 + col;

  const float* Qrow  = Q    + ((size_t)bh * SEQ + qglob) * DH;
  const float* Kb    = K    + (size_t)bh * SEQ * DH;
  const float* Vb    = V    + (size_t)bh * SEQ * DH;
  const float* biasp = Bias + ((size_t)b * SEQ + qglob) * SEQ;
  const int*   maskp = Mask + ((size_t)b * SEQ + qglob) * SEQ;

  // ---- Q fragments (B operand of QK^T): elem j of slice s <-> d = 32s+8g+j
  s16x8 qhi[4], qlo[4];
#pragma unroll
  for (int s = 0; s < 4; ++s) {
    const float* qp = Qrow + 32 * s + 8 * g;
    f32x4 a  = *(const f32x4*)qp;
    f32x4 c4 = *(const f32x4*)(qp + 4);
    Frag8 fh, fl;
    uint32_t h0, l0, h1, l1;
    cvt_hilo(a.x, h0, l0);  cvt_hilo(a.y, h1, l1);
    fh.u[0] = h0 | (h1 << 16); fl.u[0] = l0 | (l1 << 16);
    cvt_hilo(a.z, h0, l0);  cvt_hilo(a.w, h1, l1);
    fh.u[1] = h0 | (h1 << 16); fl.u[1] = l0 | (l1 << 16);
    cvt_hilo(c4.x, h0, l0); cvt_hilo(c4.y, h1, l1);
    fh.u[2] = h0 | (h1 << 16); fl.u[2] = l0 | (l1 << 16);
    cvt_hilo(c4.z, h0, l0); cvt_hilo(c4.w, h1, l1);
    fh.u[3] = h0 | (h1 << 16); fl.u[3] = l0 | (l1 << 16);
    qhi[s] = fh.v; qlo[s] = fl.v;
  }

  f32x4 acc[8];   // O^T tiles: acc[dt] covers d = 16*dt + 4g + r, col q
#pragma unroll
  for (int dt = 0; dt < 8; ++dt) acc[dt] = f32x4{0.f, 0.f, 0.f, 0.f};
  float m = NEG_INF_F, lsum = 0.f;

  const int srow = tid >> 3;  // staging row 0..31
  const int sc   = tid & 7;   // 8 threads per row
  const float scale = 1.0f / sqrtf((float)DH);

  const int wqmax = qt * 64 + w * 16 + 15;   // this wave's max q
  const int nch = 2 * qt + 2;                // causal: skip chunks past diagonal

  for (int cchunk = 0; cchunk < nch; ++cchunk) {
    const int k0 = cchunk * KC;
    __syncthreads();
    // ---- stage K,V chunk (f32 -> bf16 hi/lo) ----
    {
      const float* krow = Kb + (size_t)(k0 + srow) * DH;
      const float* vrow = Vb + (size_t)(k0 + srow) * DH;
      const int ksub = srow >> 2;
      const int kpos = srow & 3;
#pragma unroll
      for (int i = 0; i < 4; ++i) {
        const int d0 = 4 * sc + 32 * i;
        f32x4 kv = *(const f32x4*)(krow + d0);
        uint32_t h0,l0,h1,l1,h2,l2,h3,l3;
        cvt_hilo(kv.x,h0,l0); cvt_hilo(kv.y,h1,l1);
        cvt_hilo(kv.z,h2,l2); cvt_hilo(kv.w,h3,l3);
        const int cc  = (sc >> 1) + 4 * i;
        const int ccs = cc ^ (srow & 7);
        const int idx = srow * 128 + ccs * 8 + (sc & 1) * 4;
        u32x2 hv, lv;
        hv.x = h0 | (h1 << 16); hv.y = h2 | (h3 << 16);
        lv.x = l0 | (l1 << 16); lv.y = l2 | (l3 << 16);
        *(u32x2*)(&sKhi[idx]) = hv;
        *(u32x2*)(&sKlo[idx]) = lv;

        f32x4 vv = *(const f32x4*)(vrow + d0);
        cvt_hilo(vv.x,h0,l0); cvt_hilo(vv.y,h1,l1);
        cvt_hilo(vv.z,h2,l2); cvt_hilo(vv.w,h3,l3);
        const int dswz = (ksub & 3) << 2;
        {
          int d = d0 + 0, dp = d ^ dswz;
          int vi = ksub * 512 + dp * 4 + kpos;
          sVhi[vi] = (short)h0; sVlo[vi] = (short)l0;
        }
        {
          int d = d0 + 1, dp = d ^ dswz;
          int vi = ksub * 512 + dp * 4 + kpos;
          sVhi[vi] = (short)h1; sVlo[vi] = (short)l1;
        }
        {
          int d = d0 + 2, dp = d ^ dswz;
          int vi = ksub * 512 + dp * 4 + kpos;
          sVhi[vi] = (short)h2; sVlo[vi] = (short)l2;
        }
        {
          int d = d0 + 3, dp = d ^ dswz;
          int vi = ksub * 512 + dp * 4 + kpos;
          sVhi[vi] = (short)h3; sVlo[vi] = (short)l3;
        }
      }
    }
    __syncthreads();

    if (k0 > wqmax) continue;   // wave-uniform: chunk fully above diagonal

    // ---- bias/mask prefetch (lane's C elements: k = k0 + 16t + 4g + r) ----
    f32x4 bias0 = *(const f32x4*)(biasp + k0 + 4 * g);
    f32x4 bias1 = *(const f32x4*)(biasp + k0 + 16 + 4 * g);
    i32x4 mu0 = *(const i32x4*)(maskp + k0 + 4 * g);
    i32x4 mu1 = *(const i32x4*)(maskp + k0 + 16 + 4 * g);

    // ---- QK^T: S^T tiles t=0,1 (A = K rows, B = Q^T), bf16x3 ----
    f32x4 sacc[2];
#pragma unroll
    for (int t = 0; t < 2; ++t) {
      const int kr = t * 16 + col;
      const int rowbase = kr * 128;
      const int sw = kr & 7;
      f32x4 sa = f32x4{0.f, 0.f, 0.f, 0.f};
#pragma unroll
      for (int s = 0; s < 4; ++s) {
        const int idx = rowbase + ((4 * s + g) ^ sw) * 8;
        const s16x8 kh = *(const s16x8*)(&sKhi[idx]);
        const s16x8 kl = *(const s16x8*)(&sKlo[idx]);
        sa = MFMA16x16x32(kh, qhi[s], sa, 0, 0, 0);
        sa = MFMA16x16x32(kh, qlo[s], sa, 0, 0, 0);
        sa = MFMA16x16x32(kl, qhi[s], sa, 0, 0, 0);
      }
      sacc[t] = sa;
    }

    // ---- online softmax (exact reference numerics) ----
    float pvv[8];
    float cmax = NEG_INF_F;
#pragma unroll
    for (int t = 0; t < 2; ++t) {
      const f32x4 bb = t ? bias1 : bias0;
      const i32x4 mu = t ? mu1 : mu0;
#pragma unroll
      for (int r = 0; r < 4; ++r) {
        const int kg = k0 + 16 * t + 4 * g + r;
        float sv = sacc[t][r] * scale + bb[r];
        bool ok = (mu[r] != 0) && (kg <= qglob);
        float sm = ok ? sv : NEG_INF_F;
        pvv[t * 4 + r] = sm;
        cmax = fmaxf(cmax, sm);
      }
    }
    cmax = fmaxf(cmax, __shfl_xor(cmax, 16, 64));
    cmax = fmaxf(cmax, __shfl_xor(cmax, 32, 64));
    const float mnew  = fmaxf(m, cmax);
    const float alpha = __expf(m - mnew);
    float psum = 0.f;
#pragma unroll
    for (int j = 0; j < 8; ++j) {
      float p = (pvv[j] == NEG_INF_F) ? 0.f : __expf(pvv[j] - mnew);
      pvv[j] = p;
      psum += p;
    }
    psum += __shfl_xor(psum, 16, 64);
    psum += __shfl_xor(psum, 32, 64);
    lsum = lsum * alpha + psum;
    m = mnew;
#pragma unroll
    for (int dt = 0; dt < 8; ++dt) acc[dt] *= alpha;

    // ---- P fragments (lane-local: pvv[j] is exactly B-frag elem j) ----
    Frag8 fph, fpl;
#pragma unroll
    for (int j = 0; j < 4; ++j) {
      uint32_t h0, l0, h1, l1;
      cvt_hilo(pvv[2 * j],     h0, l0);
      cvt_hilo(pvv[2 * j + 1], h1, l1);
      fph.u[j] = h0 | (h1 << 16);
      fpl.u[j] = l0 | (l1 << 16);
    }
    const s16x8 ph = fph.v, pl = fpl.v;

    // ---- PV: O^T += V^T · P^T (A = V^T frags from interleaved LDS) ----
    const int dxor = col ^ (g << 2);
#pragma unroll
    for (int dt = 0; dt < 8; ++dt) {
      const int dp = dt * 16 + dxor;
      const int ia = (g * 128 + dp) * 4;         // k = 4g..4g+3
      const int ib = ((g + 4) * 128 + dp) * 4;   // k = 16+4g..16+4g+3
      u32x2 vha = *(const u32x2*)(&sVhi[ia]);
      u32x2 vhb = *(const u32x2*)(&sVhi[ib]);
      u32x2 vla = *(const u32x2*)(&sVlo[ia]);
      u32x2 vlb = *(const u32x2*)(&sVlo[ib]);
      Frag8 fvh, fvl;
      fvh.u[0] = vha.x; fvh.u[1] = vha.y; fvh.u[2] = vhb.x; fvh.u[3] = vhb.y;
      fvl.u[0] = vla.x; fvl.u[1] = vla.y; fvl.u[2] = vlb.x; fvl.u[3] = vlb.y;
      acc[dt] = MFMA16x16x32(fvh.v, ph, acc[dt], 0, 0, 0);
      acc[dt] = MFMA16x16x32(fvh.v, pl, acc[dt], 0, 0, 0);
      acc[dt] = MFMA16x16x32(fvl.v, ph, acc[dt], 0, 0, 0);
    }
  }

  // ---- epilogue: normalize, store O (lane holds q=col, d=16dt+4g+r) ----
  const float inv = 1.0f / fmaxf(lsum, 1e-9f);
  float* op = Out + ((size_t)bh * SEQ + qglob) * DH;
#pragma unroll
  for (int dt = 0; dt < 8; ++dt) {
    f32x4 o = acc[dt] * inv;
    *(f32x4*)(op + dt * 16 + 4 * g) = o;
  }
}

extern "C" void kernel_launch(void* const* d_in, const int* in_sizes, int n_in,
                              void* d_out, int out_size, void* d_ws, size_t ws_size,
                              hipStream_t stream) {
  const float* Q    = (const float*)d_in[0];
  const float* K    = (const float*)d_in[1];
  const float* V    = (const float*)d_in[2];
  const float* Bias = (const float*)d_in[3];
  const int*   Mask = (const int*)d_in[4];  // harness passes bool as int32
  float* Outp = (float*)d_out;

  // grid: (b,h) slow, q-tile fast -> same-(b,h) wgs temporally adjacent (L3 reuse)
  attn_fused<<<dim3(NB * NH * 4), dim3(256), 0, stream>>>(Q, K, V, Bias, Mask, Outp);
}